// Round 1
// baseline (809.757 us; speedup 1.0000x reference)
//
#include <hip/hip_runtime.h>

// ---------------------------------------------------------------------------
// 2-layer GCN encoder (PyG GCNConv semantics), f32 end-to-end.
// Pipeline:
//   1. cnt[i]   = #edges with dst==i              (atomics)
//   2. dinv[i]  = 1/sqrt(cnt[i]+1)                 (self-loop included)
//   3. rowoff   = exclusive_scan(cnt)              (3-phase scan)
//   4. col      = CSR column (src) list            (atomic cursor fill)
//   5. buf1     = Ahat @ X            [N,256]      (gather aggregate)
//   6. buf1     = relu(buf1 @ W1 + b1) in-place    (row-local tiled GEMM)
//   7. buf2     = buf1 @ W2           [N,128]      (tiled GEMM)
//   8. out      = relu(Ahat @ buf2 + b2)           (gather aggregate)
// ---------------------------------------------------------------------------

constexpr int SCAN_CHUNK = 2048;   // 256 threads * 8 items

__global__ __launch_bounds__(256) void count_dst_kernel(const int* __restrict__ dst, int E,
                                                        int* __restrict__ cnt) {
    int e = blockIdx.x * 256 + threadIdx.x;
    if (e < E) atomicAdd(&cnt[dst[e]], 1);
}

__global__ __launch_bounds__(256) void dinv_kernel(const int* __restrict__ cnt,
                                                   float* __restrict__ dinv, int N) {
    int i = blockIdx.x * 256 + threadIdx.x;
    if (i < N) dinv[i] = 1.0f / sqrtf((float)(cnt[i] + 1));
}

__global__ __launch_bounds__(256) void scan_phase1(const int* __restrict__ cnt, int N,
                                                   int* __restrict__ bsum) {
    __shared__ int lds[256];
    int tid = threadIdx.x;
    int base = blockIdx.x * SCAN_CHUNK + tid * 8;
    int s = 0;
#pragma unroll
    for (int j = 0; j < 8; ++j) {
        int idx = base + j;
        if (idx < N) s += cnt[idx];
    }
    lds[tid] = s;
    __syncthreads();
    for (int o = 128; o > 0; o >>= 1) {
        if (tid < o) lds[tid] += lds[tid + o];
        __syncthreads();
    }
    if (tid == 0) bsum[blockIdx.x] = lds[0];
}

__global__ void scan_phase2(int* __restrict__ bsum, int nb, int* __restrict__ rowoff,
                            int N, int E) {
    if (threadIdx.x == 0) {
        int run = 0;
        for (int b = 0; b < nb; ++b) {
            int v = bsum[b];
            bsum[b] = run;
            run += v;
        }
        rowoff[N] = E;
    }
}

__global__ __launch_bounds__(256) void scan_phase3(const int* __restrict__ cnt, int N,
                                                   const int* __restrict__ bsum,
                                                   int* __restrict__ rowoff) {
    __shared__ int lds[256];
    int tid = threadIdx.x;
    int base = blockIdx.x * SCAN_CHUNK + tid * 8;
    int v[8];
    int tsum = 0;
#pragma unroll
    for (int j = 0; j < 8; ++j) {
        int idx = base + j;
        v[j] = (idx < N) ? cnt[idx] : 0;
        tsum += v[j];
    }
    lds[tid] = tsum;
    __syncthreads();
    // Hillis-Steele inclusive scan over thread sums
    for (int off = 1; off < 256; off <<= 1) {
        int x = (tid >= off) ? lds[tid - off] : 0;
        __syncthreads();
        lds[tid] += x;
        __syncthreads();
    }
    int run = bsum[blockIdx.x] + lds[tid] - tsum;  // exclusive base for this thread
#pragma unroll
    for (int j = 0; j < 8; ++j) {
        int idx = base + j;
        if (idx < N) rowoff[idx] = run;
        run += v[j];
    }
}

__global__ __launch_bounds__(256) void fill_csr(const int* __restrict__ src,
                                                const int* __restrict__ dst, int E,
                                                const int* __restrict__ rowoff,
                                                int* __restrict__ cursor,
                                                int* __restrict__ col) {
    int e = blockIdx.x * 256 + threadIdx.x;
    if (e < E) {
        int d = dst[e];
        int pos = atomicAdd(&cursor[d], 1);
        col[rowoff[d] + pos] = src[e];
    }
}

// out[i,:] = dinv[i] * ( dinv[i]*h[i,:] + sum_e dinv[src_e]*h[src_e,:] ),  F=256
__global__ __launch_bounds__(64) void aggregate256(const float* __restrict__ h,
                                                   const float* __restrict__ dinv,
                                                   const int* __restrict__ rowoff,
                                                   const int* __restrict__ col,
                                                   float* __restrict__ out) {
    int i = blockIdx.x;
    int lane = threadIdx.x;
    float di = dinv[i];
    const float4* hv = (const float4*)h;
    float4 v = hv[(size_t)i * 64 + lane];
    float4 acc;
    acc.x = di * v.x; acc.y = di * v.y; acc.z = di * v.z; acc.w = di * v.w;
    int e0 = rowoff[i], e1 = rowoff[i + 1];
    for (int e = e0; e < e1; ++e) {
        int s = col[e];
        float w = dinv[s];
        float4 u = hv[(size_t)s * 64 + lane];
        acc.x += w * u.x; acc.y += w * u.y; acc.z += w * u.z; acc.w += w * u.w;
    }
    acc.x *= di; acc.y *= di; acc.z *= di; acc.w *= di;
    ((float4*)out)[(size_t)i * 64 + lane] = acc;
}

// F=128 variant with fused bias + relu epilogue (final layer)
__global__ __launch_bounds__(64) void aggregate128_bias_relu(const float* __restrict__ h,
                                                             const float* __restrict__ dinv,
                                                             const int* __restrict__ rowoff,
                                                             const int* __restrict__ col,
                                                             const float* __restrict__ bias,
                                                             float* __restrict__ out) {
    int i = blockIdx.x;
    int lane = threadIdx.x;
    float di = dinv[i];
    const float2* hv = (const float2*)h;
    float2 v = hv[(size_t)i * 64 + lane];
    float2 acc;
    acc.x = di * v.x; acc.y = di * v.y;
    int e0 = rowoff[i], e1 = rowoff[i + 1];
    for (int e = e0; e < e1; ++e) {
        int s = col[e];
        float w = dinv[s];
        float2 u = hv[(size_t)s * 64 + lane];
        acc.x += w * u.x; acc.y += w * u.y;
    }
    float2 bb = ((const float2*)bias)[lane];
    acc.x = fmaxf(acc.x * di + bb.x, 0.f);
    acc.y = fmaxf(acc.y * di + bb.y, 0.f);
    ((float2*)out)[(size_t)i * 64 + lane] = acc;
}

// Row-local tiled f32 GEMM: out[M,NC] = A[M,256] @ W[256,NC] (+bias, relu).
// One block computes 64 rows x ALL NC cols -> in-place safe (out may alias A).
// Thread tile: 4 rows x CPT cols; per-thread cols are g*64 + tx*4 + l
// (16B/lane, 64B lane stride in LDS -> 2-way bank access = free).
template <int NC, bool BIAS_RELU>
__global__ __launch_bounds__(256) void gemm_rows(const float* __restrict__ A,
                                                 const float* __restrict__ W,
                                                 const float* __restrict__ bias,
                                                 float* __restrict__ out, int M) {
    constexpr int BK = 16;
    constexpr int CPT = NC / 16;   // 16 (NC=256) or 8 (NC=128)
    constexpr int GRP = CPT / 4;   // float4 groups per thread
    __shared__ float As[BK][68];   // transposed A tile, pad keeps 16B align, 2-way banks
    __shared__ float Bs[BK][NC];

    const int tid = threadIdx.x;
    const int row0 = blockIdx.x * 64;
    const int tx = tid & 15;
    const int ty = (tid >> 4) << 2;  // 0..60 step 4

    float acc[4][CPT];
#pragma unroll
    for (int r = 0; r < 4; ++r)
#pragma unroll
        for (int j = 0; j < CPT; ++j) acc[r][j] = 0.f;

    const int ar = tid >> 2;         // row within tile this thread stages
    const int ak = (tid & 3) << 2;   // k offset within BK chunk
    int arr = row0 + ar;
    if (arr >= M) arr = M - 1;       // clamp: last block only, row owned by same block
    const float* aptr = A + (size_t)arr * 256 + ak;

    for (int k0 = 0; k0 < 256; k0 += BK) {
        // stage A 64x16 chunk, transposed
        float4 a4 = *(const float4*)(aptr + k0);
        As[ak + 0][ar] = a4.x;
        As[ak + 1][ar] = a4.y;
        As[ak + 2][ar] = a4.z;
        As[ak + 3][ar] = a4.w;
        // stage B 16xNC chunk
        constexpr int PASSES = (BK * NC) / 1024;
#pragma unroll
        for (int p = 0; p < PASSES; ++p) {
            int idx = (p * 256 + tid) * 4;
            int kr = idx / NC;
            int c = idx - kr * NC;
            *(float4*)&Bs[kr][c] = *(const float4*)(W + (size_t)(k0 + kr) * NC + c);
        }
        __syncthreads();
#pragma unroll
        for (int k = 0; k < BK; ++k) {
            float4 av = *(const float4*)&As[k][ty];
            float a[4] = {av.x, av.y, av.z, av.w};
            float b[CPT];
#pragma unroll
            for (int g = 0; g < GRP; ++g) {
                float4 bv = *(const float4*)&Bs[k][g * 64 + tx * 4];
                b[g * 4 + 0] = bv.x;
                b[g * 4 + 1] = bv.y;
                b[g * 4 + 2] = bv.z;
                b[g * 4 + 3] = bv.w;
            }
#pragma unroll
            for (int r = 0; r < 4; ++r)
#pragma unroll
                for (int j = 0; j < CPT; ++j) acc[r][j] = fmaf(a[r], b[j], acc[r][j]);
        }
        __syncthreads();
    }

    float4 bb[GRP];
    if constexpr (BIAS_RELU) {
#pragma unroll
        for (int g = 0; g < GRP; ++g) bb[g] = *(const float4*)(bias + g * 64 + tx * 4);
    }
#pragma unroll
    for (int r = 0; r < 4; ++r) {
        int row = row0 + ty + r;
        if (row < M) {
#pragma unroll
            for (int g = 0; g < GRP; ++g) {
                float4 v;
                v.x = acc[r][g * 4 + 0];
                v.y = acc[r][g * 4 + 1];
                v.z = acc[r][g * 4 + 2];
                v.w = acc[r][g * 4 + 3];
                if constexpr (BIAS_RELU) {
                    v.x = fmaxf(v.x + bb[g].x, 0.f);
                    v.y = fmaxf(v.y + bb[g].y, 0.f);
                    v.z = fmaxf(v.z + bb[g].z, 0.f);
                    v.w = fmaxf(v.w + bb[g].w, 0.f);
                }
                *(float4*)(out + (size_t)row * NC + g * 64 + tx * 4) = v;
            }
        }
    }
}

extern "C" void kernel_launch(void* const* d_in, const int* in_sizes, int n_in,
                              void* d_out, int out_size, void* d_ws, size_t ws_size,
                              hipStream_t stream) {
    const float* x  = (const float*)d_in[0];
    const int*   ei = (const int*)d_in[1];
    const float* W1 = (const float*)d_in[2];
    const float* b1 = (const float*)d_in[3];
    const float* W2 = (const float*)d_in[4];
    const float* b2 = (const float*)d_in[5];
    float* out = (float*)d_out;

    const int N = in_sizes[0] / 256;
    const int E = in_sizes[1] / 2;
    const int* src = ei;
    const int* dst = ei + E;

    char* ws = (char*)d_ws;
    size_t off = 0;
    auto alloc = [&](size_t bytes) -> char* {
        char* p = ws + off;
        off += (bytes + 255) & ~(size_t)255;
        return p;
    };
    int*   cnt    = (int*)alloc((size_t)N * 4);
    int*   cursor = (int*)alloc((size_t)N * 4);
    int*   rowoff = (int*)alloc((size_t)(N + 1) * 4);
    int*   bsum   = (int*)alloc(4096);
    float* dinv   = (float*)alloc((size_t)N * 4);
    int*   col    = (int*)alloc((size_t)E * 4);
    float* buf1   = (float*)alloc((size_t)N * 256 * 4);
    float* buf2   = (float*)alloc((size_t)N * 128 * 4);

    const int NB = (N + SCAN_CHUNK - 1) / SCAN_CHUNK;

    hipMemsetAsync(cnt, 0, (size_t)N * 4, stream);
    hipMemsetAsync(cursor, 0, (size_t)N * 4, stream);

    count_dst_kernel<<<(E + 255) / 256, 256, 0, stream>>>(dst, E, cnt);
    dinv_kernel<<<(N + 255) / 256, 256, 0, stream>>>(cnt, dinv, N);
    scan_phase1<<<NB, 256, 0, stream>>>(cnt, N, bsum);
    scan_phase2<<<1, 64, 0, stream>>>(bsum, NB, rowoff, N, E);
    scan_phase3<<<NB, 256, 0, stream>>>(cnt, N, bsum, rowoff);
    fill_csr<<<(E + 255) / 256, 256, 0, stream>>>(src, dst, E, rowoff, cursor, col);

    // layer 1: aggregate X (256-wide), then in-place row GEMM with bias+relu
    aggregate256<<<N, 64, 0, stream>>>(x, dinv, rowoff, col, buf1);
    const int GB = (N + 63) / 64;
    gemm_rows<256, true><<<GB, 256, 0, stream>>>(buf1, W1, b1, buf1, N);

    // layer 2: GEMM to 128-wide, then aggregate with fused bias+relu
    gemm_rows<128, false><<<GB, 256, 0, stream>>>(buf1, W2, nullptr, buf2, N);
    aggregate128_bias_relu<<<N, 64, 0, stream>>>(buf2, dinv, rowoff, col, b2, out);
}

// Round 2
// 805.140 us; speedup vs baseline: 1.0057x; 1.0057x over previous
//
#include <hip/hip_runtime.h>

// ---------------------------------------------------------------------------
// 2-layer GCN encoder (PyG GCNConv semantics), f32 end-to-end.
// Pipeline:
//   1. cnt[i]   = #edges with dst==i              (atomics)
//   2. dinv[i]  = 1/sqrt(cnt[i]+1)                 (self-loop included)
//   3. rowoff   = exclusive_scan(cnt)              (3-phase scan)
//   4. col      = CSR column (src) list            (atomic cursor fill)
//   5. buf1     = Ahat @ X            [N,256]      (gather aggregate, unroll-8)
//   6. buf1     = relu(buf1 @ W1 + b1) in-place    (row-local tiled GEMM)
//   7. buf2     = (buf1 @ W2) * dinv[row]          (tiled GEMM, dinv folded)
//   8. out      = relu(di*(buf2[i]+sum buf2[src]) + b2)  (gather, unroll-8)
// ---------------------------------------------------------------------------

constexpr int SCAN_CHUNK = 2048;   // 256 threads * 8 items

__global__ __launch_bounds__(256) void count_dst_kernel(const int* __restrict__ dst, int E,
                                                        int* __restrict__ cnt) {
    int e = blockIdx.x * 256 + threadIdx.x;
    if (e < E) atomicAdd(&cnt[dst[e]], 1);
}

__global__ __launch_bounds__(256) void dinv_kernel(const int* __restrict__ cnt,
                                                   float* __restrict__ dinv, int N) {
    int i = blockIdx.x * 256 + threadIdx.x;
    if (i < N) dinv[i] = 1.0f / sqrtf((float)(cnt[i] + 1));
}

__global__ __launch_bounds__(256) void scan_phase1(const int* __restrict__ cnt, int N,
                                                   int* __restrict__ bsum) {
    __shared__ int lds[256];
    int tid = threadIdx.x;
    int base = blockIdx.x * SCAN_CHUNK + tid * 8;
    int s = 0;
#pragma unroll
    for (int j = 0; j < 8; ++j) {
        int idx = base + j;
        if (idx < N) s += cnt[idx];
    }
    lds[tid] = s;
    __syncthreads();
    for (int o = 128; o > 0; o >>= 1) {
        if (tid < o) lds[tid] += lds[tid + o];
        __syncthreads();
    }
    if (tid == 0) bsum[blockIdx.x] = lds[0];
}

__global__ void scan_phase2(int* __restrict__ bsum, int nb, int* __restrict__ rowoff,
                            int N, int E) {
    if (threadIdx.x == 0) {
        int run = 0;
        for (int b = 0; b < nb; ++b) {
            int v = bsum[b];
            bsum[b] = run;
            run += v;
        }
        rowoff[N] = E;
    }
}

__global__ __launch_bounds__(256) void scan_phase3(const int* __restrict__ cnt, int N,
                                                   const int* __restrict__ bsum,
                                                   int* __restrict__ rowoff) {
    __shared__ int lds[256];
    int tid = threadIdx.x;
    int base = blockIdx.x * SCAN_CHUNK + tid * 8;
    int v[8];
    int tsum = 0;
#pragma unroll
    for (int j = 0; j < 8; ++j) {
        int idx = base + j;
        v[j] = (idx < N) ? cnt[idx] : 0;
        tsum += v[j];
    }
    lds[tid] = tsum;
    __syncthreads();
    // Hillis-Steele inclusive scan over thread sums
    for (int off = 1; off < 256; off <<= 1) {
        int x = (tid >= off) ? lds[tid - off] : 0;
        __syncthreads();
        lds[tid] += x;
        __syncthreads();
    }
    int run = bsum[blockIdx.x] + lds[tid] - tsum;  // exclusive base for this thread
#pragma unroll
    for (int j = 0; j < 8; ++j) {
        int idx = base + j;
        if (idx < N) rowoff[idx] = run;
        run += v[j];
    }
}

__global__ __launch_bounds__(256) void fill_csr(const int* __restrict__ src,
                                                const int* __restrict__ dst, int E,
                                                const int* __restrict__ rowoff,
                                                int* __restrict__ cursor,
                                                int* __restrict__ col) {
    int e = blockIdx.x * 256 + threadIdx.x;
    if (e < E) {
        int d = dst[e];
        int pos = atomicAdd(&cursor[d], 1);
        col[rowoff[d] + pos] = src[e];
    }
}

// out[i,:] = dinv[i] * ( dinv[i]*h[i,:] + sum_e dinv[src_e]*h[src_e,:] ),  F=256
// Edge loop unrolled 8-deep: 8 independent 1KB row gathers in flight per wave.
__global__ __launch_bounds__(64) void aggregate256(const float* __restrict__ h,
                                                   const float* __restrict__ dinv,
                                                   const int* __restrict__ rowoff,
                                                   const int* __restrict__ col,
                                                   float* __restrict__ out) {
    int i = blockIdx.x;
    int lane = threadIdx.x;
    float di = dinv[i];
    const float4* __restrict__ hv = (const float4*)h;
    float4 v = hv[(size_t)i * 64 + lane];
    float ax = di * v.x, ay = di * v.y, az = di * v.z, aw = di * v.w;
    int e0 = rowoff[i], e1 = rowoff[i + 1];
    int e = e0;
    for (; e + 8 <= e1; e += 8) {
        int s[8];
#pragma unroll
        for (int j = 0; j < 8; ++j) s[j] = col[e + j];
        float w[8];
#pragma unroll
        for (int j = 0; j < 8; ++j) w[j] = dinv[s[j]];
        float4 u[8];
#pragma unroll
        for (int j = 0; j < 8; ++j) u[j] = hv[(size_t)s[j] * 64 + lane];
#pragma unroll
        for (int j = 0; j < 8; ++j) {
            ax = fmaf(w[j], u[j].x, ax);
            ay = fmaf(w[j], u[j].y, ay);
            az = fmaf(w[j], u[j].z, az);
            aw = fmaf(w[j], u[j].w, aw);
        }
    }
    // tail (<8 edges), 4-deep then scalar
    if (e + 4 <= e1) {
        int s[4];
#pragma unroll
        for (int j = 0; j < 4; ++j) s[j] = col[e + j];
        float w[4];
#pragma unroll
        for (int j = 0; j < 4; ++j) w[j] = dinv[s[j]];
        float4 u[4];
#pragma unroll
        for (int j = 0; j < 4; ++j) u[j] = hv[(size_t)s[j] * 64 + lane];
#pragma unroll
        for (int j = 0; j < 4; ++j) {
            ax = fmaf(w[j], u[j].x, ax);
            ay = fmaf(w[j], u[j].y, ay);
            az = fmaf(w[j], u[j].z, az);
            aw = fmaf(w[j], u[j].w, aw);
        }
        e += 4;
    }
    for (; e < e1; ++e) {
        int s = col[e];
        float w = dinv[s];
        float4 u = hv[(size_t)s * 64 + lane];
        ax = fmaf(w, u.x, ax);
        ay = fmaf(w, u.y, ay);
        az = fmaf(w, u.z, az);
        aw = fmaf(w, u.w, aw);
    }
    float4 acc;
    acc.x = ax * di; acc.y = ay * di; acc.z = az * di; acc.w = aw * di;
    ((float4*)out)[(size_t)i * 64 + lane] = acc;
}

// F=128 final aggregate. h is PRE-SCALED by dinv[src] (folded into GEMM2
// epilogue), so no per-edge dinv gather: out[i]=relu(di*(h[i]+sum h[src])+b).
__global__ __launch_bounds__(64) void aggregate128_bias_relu(const float* __restrict__ h,
                                                             const float* __restrict__ dinv,
                                                             const int* __restrict__ rowoff,
                                                             const int* __restrict__ col,
                                                             const float* __restrict__ bias,
                                                             float* __restrict__ out) {
    int i = blockIdx.x;
    int lane = threadIdx.x;
    float di = dinv[i];
    const float2* __restrict__ hv = (const float2*)h;
    float2 v = hv[(size_t)i * 64 + lane];
    float ax = v.x, ay = v.y;
    int e0 = rowoff[i], e1 = rowoff[i + 1];
    int e = e0;
    for (; e + 8 <= e1; e += 8) {
        int s[8];
#pragma unroll
        for (int j = 0; j < 8; ++j) s[j] = col[e + j];
        float2 u[8];
#pragma unroll
        for (int j = 0; j < 8; ++j) u[j] = hv[(size_t)s[j] * 64 + lane];
#pragma unroll
        for (int j = 0; j < 8; ++j) {
            ax += u[j].x;
            ay += u[j].y;
        }
    }
    if (e + 4 <= e1) {
        int s[4];
#pragma unroll
        for (int j = 0; j < 4; ++j) s[j] = col[e + j];
        float2 u[4];
#pragma unroll
        for (int j = 0; j < 4; ++j) u[j] = hv[(size_t)s[j] * 64 + lane];
#pragma unroll
        for (int j = 0; j < 4; ++j) {
            ax += u[j].x;
            ay += u[j].y;
        }
        e += 4;
    }
    for (; e < e1; ++e) {
        float2 u = hv[(size_t)col[e] * 64 + lane];
        ax += u.x;
        ay += u.y;
    }
    float2 bb = ((const float2*)bias)[lane];
    float2 r;
    r.x = fmaxf(fmaf(ax, di, bb.x), 0.f);
    r.y = fmaxf(fmaf(ay, di, bb.y), 0.f);
    ((float2*)out)[(size_t)i * 64 + lane] = r;
}

// Row-local tiled f32 GEMM: out[M,NC] = A[M,256] @ W[256,NC] (+bias/relu OR
// per-row scale). One block computes 64 rows x ALL NC cols -> in-place safe.
template <int NC, bool BIAS_RELU, bool ROWSCALE>
__global__ __launch_bounds__(256) void gemm_rows(const float* __restrict__ A,
                                                 const float* __restrict__ W,
                                                 const float* __restrict__ bias,
                                                 const float* __restrict__ rowscale,
                                                 float* __restrict__ out, int M) {
    constexpr int BK = 16;
    constexpr int CPT = NC / 16;   // 16 (NC=256) or 8 (NC=128)
    constexpr int GRP = CPT / 4;   // float4 groups per thread
    __shared__ float As[BK][68];   // transposed A tile, pad keeps 16B align
    __shared__ float Bs[BK][NC];

    const int tid = threadIdx.x;
    const int row0 = blockIdx.x * 64;
    const int tx = tid & 15;
    const int ty = (tid >> 4) << 2;  // 0..60 step 4

    float acc[4][CPT];
#pragma unroll
    for (int r = 0; r < 4; ++r)
#pragma unroll
        for (int j = 0; j < CPT; ++j) acc[r][j] = 0.f;

    const int ar = tid >> 2;         // row within tile this thread stages
    const int ak = (tid & 3) << 2;   // k offset within BK chunk
    int arr = row0 + ar;
    if (arr >= M) arr = M - 1;       // clamp: last block only, row owned by same block
    const float* aptr = A + (size_t)arr * 256 + ak;

    for (int k0 = 0; k0 < 256; k0 += BK) {
        // stage A 64x16 chunk, transposed
        float4 a4 = *(const float4*)(aptr + k0);
        As[ak + 0][ar] = a4.x;
        As[ak + 1][ar] = a4.y;
        As[ak + 2][ar] = a4.z;
        As[ak + 3][ar] = a4.w;
        // stage B 16xNC chunk
        constexpr int PASSES = (BK * NC) / 1024;
#pragma unroll
        for (int p = 0; p < PASSES; ++p) {
            int idx = (p * 256 + tid) * 4;
            int kr = idx / NC;
            int c = idx - kr * NC;
            *(float4*)&Bs[kr][c] = *(const float4*)(W + (size_t)(k0 + kr) * NC + c);
        }
        __syncthreads();
#pragma unroll
        for (int k = 0; k < BK; ++k) {
            float4 av = *(const float4*)&As[k][ty];
            float a[4] = {av.x, av.y, av.z, av.w};
            float b[CPT];
#pragma unroll
            for (int g = 0; g < GRP; ++g) {
                float4 bv = *(const float4*)&Bs[k][g * 64 + tx * 4];
                b[g * 4 + 0] = bv.x;
                b[g * 4 + 1] = bv.y;
                b[g * 4 + 2] = bv.z;
                b[g * 4 + 3] = bv.w;
            }
#pragma unroll
            for (int r = 0; r < 4; ++r)
#pragma unroll
                for (int j = 0; j < CPT; ++j) acc[r][j] = fmaf(a[r], b[j], acc[r][j]);
        }
        __syncthreads();
    }

    float4 bb[GRP];
    if constexpr (BIAS_RELU) {
#pragma unroll
        for (int g = 0; g < GRP; ++g) bb[g] = *(const float4*)(bias + g * 64 + tx * 4);
    }
#pragma unroll
    for (int r = 0; r < 4; ++r) {
        int row = row0 + ty + r;
        if (row < M) {
            float rs = 1.0f;
            if constexpr (ROWSCALE) rs = rowscale[row];
#pragma unroll
            for (int g = 0; g < GRP; ++g) {
                float4 v;
                v.x = acc[r][g * 4 + 0];
                v.y = acc[r][g * 4 + 1];
                v.z = acc[r][g * 4 + 2];
                v.w = acc[r][g * 4 + 3];
                if constexpr (BIAS_RELU) {
                    v.x = fmaxf(v.x + bb[g].x, 0.f);
                    v.y = fmaxf(v.y + bb[g].y, 0.f);
                    v.z = fmaxf(v.z + bb[g].z, 0.f);
                    v.w = fmaxf(v.w + bb[g].w, 0.f);
                }
                if constexpr (ROWSCALE) {
                    v.x *= rs; v.y *= rs; v.z *= rs; v.w *= rs;
                }
                *(float4*)(out + (size_t)row * NC + g * 64 + tx * 4) = v;
            }
        }
    }
}

extern "C" void kernel_launch(void* const* d_in, const int* in_sizes, int n_in,
                              void* d_out, int out_size, void* d_ws, size_t ws_size,
                              hipStream_t stream) {
    const float* x  = (const float*)d_in[0];
    const int*   ei = (const int*)d_in[1];
    const float* W1 = (const float*)d_in[2];
    const float* b1 = (const float*)d_in[3];
    const float* W2 = (const float*)d_in[4];
    const float* b2 = (const float*)d_in[5];
    float* out = (float*)d_out;

    const int N = in_sizes[0] / 256;
    const int E = in_sizes[1] / 2;
    const int* src = ei;
    const int* dst = ei + E;

    char* ws = (char*)d_ws;
    size_t off = 0;
    auto alloc = [&](size_t bytes) -> char* {
        char* p = ws + off;
        off += (bytes + 255) & ~(size_t)255;
        return p;
    };
    int*   cnt    = (int*)alloc((size_t)N * 4);
    int*   cursor = (int*)alloc((size_t)N * 4);
    int*   rowoff = (int*)alloc((size_t)(N + 1) * 4);
    int*   bsum   = (int*)alloc(4096);
    float* dinv   = (float*)alloc((size_t)N * 4);
    int*   col    = (int*)alloc((size_t)E * 4);
    float* buf1   = (float*)alloc((size_t)N * 256 * 4);
    float* buf2   = (float*)alloc((size_t)N * 128 * 4);

    const int NB = (N + SCAN_CHUNK - 1) / SCAN_CHUNK;

    hipMemsetAsync(cnt, 0, (size_t)N * 4, stream);
    hipMemsetAsync(cursor, 0, (size_t)N * 4, stream);

    count_dst_kernel<<<(E + 255) / 256, 256, 0, stream>>>(dst, E, cnt);
    dinv_kernel<<<(N + 255) / 256, 256, 0, stream>>>(cnt, dinv, N);
    scan_phase1<<<NB, 256, 0, stream>>>(cnt, N, bsum);
    scan_phase2<<<1, 64, 0, stream>>>(bsum, NB, rowoff, N, E);
    scan_phase3<<<NB, 256, 0, stream>>>(cnt, N, bsum, rowoff);
    fill_csr<<<(E + 255) / 256, 256, 0, stream>>>(src, dst, E, rowoff, cursor, col);

    // layer 1: aggregate X (256-wide), then in-place row GEMM with bias+relu
    aggregate256<<<N, 64, 0, stream>>>(x, dinv, rowoff, col, buf1);
    const int GB = (N + 63) / 64;
    gemm_rows<256, true, false><<<GB, 256, 0, stream>>>(buf1, W1, b1, nullptr, buf1, N);

    // layer 2: GEMM to 128-wide with dinv folded into epilogue, then aggregate
    gemm_rows<128, false, true><<<GB, 256, 0, stream>>>(buf1, W2, nullptr, dinv, buf2, N);
    aggregate128_bias_relu<<<N, 64, 0, stream>>>(buf2, dinv, rowoff, col, b2, out);
}

// Round 3
// 647.057 us; speedup vs baseline: 1.2514x; 1.2443x over previous
//
#include <hip/hip_runtime.h>
#include <hip/hip_fp16.h>

// ---------------------------------------------------------------------------
// 2-layer GCN encoder (PyG GCNConv semantics). Gathers in fp16, math in f32.
// Pipeline:
//   1. cnt[i]   = #edges with dst==i              (atomics)
//   2. dinv[i]  = 1/sqrt(cnt[i]+1)                 (self-loop included)
//   3. rowoff   = exclusive_scan(cnt)              (3-phase scan)
//   4. col      = CSR column (src) list            (atomic cursor fill)
//   5. xh       = fp16(x)                          (pack, halves gather bytes)
//   6. buf1     = Ahat @ xh           [N,256] f32  (gather aggregate)
//   7. buf1     = relu(buf1 @ W1 + b1) in-place    (row-local tiled GEMM)
//   8. buf2h    = fp16((buf1 @ W2) * dinv[row])    (tiled GEMM, fp16 epilogue)
//   9. out      = relu(di*(buf2h[i]+sum buf2h[src]) + b2)  (gather)
// ---------------------------------------------------------------------------

constexpr int SCAN_CHUNK = 2048;   // 256 threads * 8 items

__global__ __launch_bounds__(256) void count_dst_kernel(const int* __restrict__ dst, int E,
                                                        int* __restrict__ cnt) {
    int e = blockIdx.x * 256 + threadIdx.x;
    if (e < E) atomicAdd(&cnt[dst[e]], 1);
}

__global__ __launch_bounds__(256) void dinv_kernel(const int* __restrict__ cnt,
                                                   float* __restrict__ dinv, int N) {
    int i = blockIdx.x * 256 + threadIdx.x;
    if (i < N) dinv[i] = 1.0f / sqrtf((float)(cnt[i] + 1));
}

__global__ __launch_bounds__(256) void scan_phase1(const int* __restrict__ cnt, int N,
                                                   int* __restrict__ bsum) {
    __shared__ int lds[256];
    int tid = threadIdx.x;
    int base = blockIdx.x * SCAN_CHUNK + tid * 8;
    int s = 0;
#pragma unroll
    for (int j = 0; j < 8; ++j) {
        int idx = base + j;
        if (idx < N) s += cnt[idx];
    }
    lds[tid] = s;
    __syncthreads();
    for (int o = 128; o > 0; o >>= 1) {
        if (tid < o) lds[tid] += lds[tid + o];
        __syncthreads();
    }
    if (tid == 0) bsum[blockIdx.x] = lds[0];
}

__global__ void scan_phase2(int* __restrict__ bsum, int nb, int* __restrict__ rowoff,
                            int N, int E) {
    if (threadIdx.x == 0) {
        int run = 0;
        for (int b = 0; b < nb; ++b) {
            int v = bsum[b];
            bsum[b] = run;
            run += v;
        }
        rowoff[N] = E;
    }
}

__global__ __launch_bounds__(256) void scan_phase3(const int* __restrict__ cnt, int N,
                                                   const int* __restrict__ bsum,
                                                   int* __restrict__ rowoff) {
    __shared__ int lds[256];
    int tid = threadIdx.x;
    int base = blockIdx.x * SCAN_CHUNK + tid * 8;
    int v[8];
    int tsum = 0;
#pragma unroll
    for (int j = 0; j < 8; ++j) {
        int idx = base + j;
        v[j] = (idx < N) ? cnt[idx] : 0;
        tsum += v[j];
    }
    lds[tid] = tsum;
    __syncthreads();
    for (int off = 1; off < 256; off <<= 1) {
        int x = (tid >= off) ? lds[tid - off] : 0;
        __syncthreads();
        lds[tid] += x;
        __syncthreads();
    }
    int run = bsum[blockIdx.x] + lds[tid] - tsum;  // exclusive base for this thread
#pragma unroll
    for (int j = 0; j < 8; ++j) {
        int idx = base + j;
        if (idx < N) rowoff[idx] = run;
        run += v[j];
    }
}

__global__ __launch_bounds__(256) void fill_csr(const int* __restrict__ src,
                                                const int* __restrict__ dst, int E,
                                                const int* __restrict__ rowoff,
                                                int* __restrict__ cursor,
                                                int* __restrict__ col) {
    int e = blockIdx.x * 256 + threadIdx.x;
    if (e < E) {
        int d = dst[e];
        int pos = atomicAdd(&cursor[d], 1);
        col[rowoff[d] + pos] = src[e];
    }
}

// f32 -> fp16 pack, 8 elems/thread
__global__ __launch_bounds__(256) void pack_half(const float* __restrict__ in,
                                                 __half* __restrict__ out, int n8) {
    int i = blockIdx.x * 256 + threadIdx.x;
    if (i < n8) {
        float4 a = ((const float4*)in)[(size_t)i * 2];
        float4 b = ((const float4*)in)[(size_t)i * 2 + 1];
        __half2 h[4];
        h[0] = __floats2half2_rn(a.x, a.y);
        h[1] = __floats2half2_rn(a.z, a.w);
        h[2] = __floats2half2_rn(b.x, b.y);
        h[3] = __floats2half2_rn(b.z, b.w);
        ((uint4*)out)[i] = *(const uint4*)h;
    }
}

// out[i,:] = dinv[i]*( dinv[i]*xh[i,:] + sum_e dinv[src]*xh[src,:] ), F=256 fp16 in, f32 out
// per lane: 4 cols as half4 (8B), wave reads 512B/row
__global__ __launch_bounds__(64) void aggregate256_h(const __half* __restrict__ xh,
                                                     const float* __restrict__ dinv,
                                                     const int* __restrict__ rowoff,
                                                     const int* __restrict__ col,
                                                     float* __restrict__ out) {
    int i = blockIdx.x;
    int lane = threadIdx.x;
    float di = dinv[i];
    const uint2* __restrict__ hv = (const uint2*)xh;  // 4 halves per slot
    uint2 raw = hv[(size_t)i * 64 + lane];
    float2 f0 = __half22float2(*(const __half2*)&raw.x);
    float2 f1 = __half22float2(*(const __half2*)&raw.y);
    float ax = di * f0.x, ay = di * f0.y, az = di * f1.x, aw = di * f1.y;
    int e0 = rowoff[i], e1 = rowoff[i + 1];
    int e = e0;
    for (; e + 8 <= e1; e += 8) {
        int s[8];
#pragma unroll
        for (int j = 0; j < 8; ++j) s[j] = col[e + j];
        float w[8];
#pragma unroll
        for (int j = 0; j < 8; ++j) w[j] = dinv[s[j]];
        uint2 u[8];
#pragma unroll
        for (int j = 0; j < 8; ++j) u[j] = hv[(size_t)s[j] * 64 + lane];
#pragma unroll
        for (int j = 0; j < 8; ++j) {
            float2 g0 = __half22float2(*(const __half2*)&u[j].x);
            float2 g1 = __half22float2(*(const __half2*)&u[j].y);
            ax = fmaf(w[j], g0.x, ax);
            ay = fmaf(w[j], g0.y, ay);
            az = fmaf(w[j], g1.x, az);
            aw = fmaf(w[j], g1.y, aw);
        }
    }
    for (; e < e1; ++e) {
        int s = col[e];
        float w = dinv[s];
        uint2 u = hv[(size_t)s * 64 + lane];
        float2 g0 = __half22float2(*(const __half2*)&u.x);
        float2 g1 = __half22float2(*(const __half2*)&u.y);
        ax = fmaf(w, g0.x, ax);
        ay = fmaf(w, g0.y, ay);
        az = fmaf(w, g1.x, az);
        aw = fmaf(w, g1.y, aw);
    }
    float4 acc;
    acc.x = ax * di; acc.y = ay * di; acc.z = az * di; acc.w = aw * di;
    ((float4*)out)[(size_t)i * 64 + lane] = acc;
}

// F=128 final aggregate over fp16 h (pre-scaled by dinv[src] in GEMM2 epilogue).
// out[i] = relu(di*(h[i]+sum h[src]) + b).  per lane: half2 (4B).
__global__ __launch_bounds__(64) void aggregate128_h_bias_relu(const __half* __restrict__ h,
                                                               const float* __restrict__ dinv,
                                                               const int* __restrict__ rowoff,
                                                               const int* __restrict__ col,
                                                               const float* __restrict__ bias,
                                                               float* __restrict__ out) {
    int i = blockIdx.x;
    int lane = threadIdx.x;
    float di = dinv[i];
    const unsigned int* __restrict__ hv = (const unsigned int*)h;  // half2 per slot
    float2 v = __half22float2(*(const __half2*)&hv[(size_t)i * 64 + lane]);
    float ax = v.x, ay = v.y;
    int e0 = rowoff[i], e1 = rowoff[i + 1];
    int e = e0;
    for (; e + 8 <= e1; e += 8) {
        int s[8];
#pragma unroll
        for (int j = 0; j < 8; ++j) s[j] = col[e + j];
        unsigned int u[8];
#pragma unroll
        for (int j = 0; j < 8; ++j) u[j] = hv[(size_t)s[j] * 64 + lane];
#pragma unroll
        for (int j = 0; j < 8; ++j) {
            float2 g = __half22float2(*(const __half2*)&u[j]);
            ax += g.x;
            ay += g.y;
        }
    }
    for (; e < e1; ++e) {
        float2 g = __half22float2(*(const __half2*)&hv[(size_t)col[e] * 64 + lane]);
        ax += g.x;
        ay += g.y;
    }
    float2 bb = ((const float2*)bias)[lane];
    float2 r;
    r.x = fmaxf(fmaf(ax, di, bb.x), 0.f);
    r.y = fmaxf(fmaf(ay, di, bb.y), 0.f);
    ((float2*)out)[(size_t)i * 64 + lane] = r;
}

// Row-local tiled f32 GEMM: out[M,NC] = A[M,256] @ W[256,NC] (+bias/relu OR
// per-row scale; optional fp16 output). One block = 64 rows x all NC cols.
template <int NC, bool BIAS_RELU, bool ROWSCALE, bool HALF_OUT>
__global__ __launch_bounds__(256) void gemm_rows(const float* __restrict__ A,
                                                 const float* __restrict__ W,
                                                 const float* __restrict__ bias,
                                                 const float* __restrict__ rowscale,
                                                 void* __restrict__ outv, int M) {
    constexpr int BK = 16;
    constexpr int CPT = NC / 16;   // 16 (NC=256) or 8 (NC=128)
    constexpr int GRP = CPT / 4;   // float4 groups per thread
    __shared__ float As[BK][68];
    __shared__ float Bs[BK][NC];

    const int tid = threadIdx.x;
    const int row0 = blockIdx.x * 64;
    const int tx = tid & 15;
    const int ty = (tid >> 4) << 2;  // 0..60 step 4

    float acc[4][CPT];
#pragma unroll
    for (int r = 0; r < 4; ++r)
#pragma unroll
        for (int j = 0; j < CPT; ++j) acc[r][j] = 0.f;

    const int ar = tid >> 2;         // row within tile this thread stages
    const int ak = (tid & 3) << 2;   // k offset within BK chunk
    int arr = row0 + ar;
    if (arr >= M) arr = M - 1;       // clamp: row still owned by this block
    const float* aptr = A + (size_t)arr * 256 + ak;

    for (int k0 = 0; k0 < 256; k0 += BK) {
        float4 a4 = *(const float4*)(aptr + k0);
        As[ak + 0][ar] = a4.x;
        As[ak + 1][ar] = a4.y;
        As[ak + 2][ar] = a4.z;
        As[ak + 3][ar] = a4.w;
        constexpr int PASSES = (BK * NC) / 1024;
#pragma unroll
        for (int p = 0; p < PASSES; ++p) {
            int idx = (p * 256 + tid) * 4;
            int kr = idx / NC;
            int c = idx - kr * NC;
            *(float4*)&Bs[kr][c] = *(const float4*)(W + (size_t)(k0 + kr) * NC + c);
        }
        __syncthreads();
#pragma unroll
        for (int k = 0; k < BK; ++k) {
            float4 av = *(const float4*)&As[k][ty];
            float a[4] = {av.x, av.y, av.z, av.w};
            float b[CPT];
#pragma unroll
            for (int g = 0; g < GRP; ++g) {
                float4 bv = *(const float4*)&Bs[k][g * 64 + tx * 4];
                b[g * 4 + 0] = bv.x;
                b[g * 4 + 1] = bv.y;
                b[g * 4 + 2] = bv.z;
                b[g * 4 + 3] = bv.w;
            }
#pragma unroll
            for (int r = 0; r < 4; ++r)
#pragma unroll
                for (int j = 0; j < CPT; ++j) acc[r][j] = fmaf(a[r], b[j], acc[r][j]);
        }
        __syncthreads();
    }

    float4 bb[GRP];
    if constexpr (BIAS_RELU) {
#pragma unroll
        for (int g = 0; g < GRP; ++g) bb[g] = *(const float4*)(bias + g * 64 + tx * 4);
    }
#pragma unroll
    for (int r = 0; r < 4; ++r) {
        int row = row0 + ty + r;
        if (row < M) {
            float rs = 1.0f;
            if constexpr (ROWSCALE) rs = rowscale[row];
#pragma unroll
            for (int g = 0; g < GRP; ++g) {
                float4 v;
                v.x = acc[r][g * 4 + 0];
                v.y = acc[r][g * 4 + 1];
                v.z = acc[r][g * 4 + 2];
                v.w = acc[r][g * 4 + 3];
                if constexpr (BIAS_RELU) {
                    v.x = fmaxf(v.x + bb[g].x, 0.f);
                    v.y = fmaxf(v.y + bb[g].y, 0.f);
                    v.z = fmaxf(v.z + bb[g].z, 0.f);
                    v.w = fmaxf(v.w + bb[g].w, 0.f);
                }
                if constexpr (ROWSCALE) {
                    v.x *= rs; v.y *= rs; v.z *= rs; v.w *= rs;
                }
                if constexpr (HALF_OUT) {
                    __half2 h[2];
                    h[0] = __floats2half2_rn(v.x, v.y);
                    h[1] = __floats2half2_rn(v.z, v.w);
                    __half* outp = (__half*)outv + (size_t)row * NC + g * 64 + tx * 4;
                    *(uint2*)outp = *(const uint2*)h;
                } else {
                    *(float4*)((float*)outv + (size_t)row * NC + g * 64 + tx * 4) = v;
                }
            }
        }
    }
}

extern "C" void kernel_launch(void* const* d_in, const int* in_sizes, int n_in,
                              void* d_out, int out_size, void* d_ws, size_t ws_size,
                              hipStream_t stream) {
    const float* x  = (const float*)d_in[0];
    const int*   ei = (const int*)d_in[1];
    const float* W1 = (const float*)d_in[2];
    const float* b1 = (const float*)d_in[3];
    const float* W2 = (const float*)d_in[4];
    const float* b2 = (const float*)d_in[5];
    float* out = (float*)d_out;

    const int N = in_sizes[0] / 256;
    const int E = in_sizes[1] / 2;
    const int* src = ei;
    const int* dst = ei + E;

    char* ws = (char*)d_ws;
    size_t off = 0;
    auto alloc = [&](size_t bytes) -> char* {
        char* p = ws + off;
        off += (bytes + 255) & ~(size_t)255;
        return p;
    };
    int*    cnt    = (int*)alloc((size_t)N * 4);
    int*    cursor = (int*)alloc((size_t)N * 4);
    int*    rowoff = (int*)alloc((size_t)(N + 1) * 4);
    int*    bsum   = (int*)alloc(4096);
    float*  dinv   = (float*)alloc((size_t)N * 4);
    int*    col    = (int*)alloc((size_t)E * 4);
    float*  buf1   = (float*)alloc((size_t)N * 256 * 4);
    // xh (N*256 fp16, dead after aggregate256_h) aliases buf2h (N*128 fp16,
    // live from GEMM2 on) — both fit in the same 51.2 MB region.
    __half* xh     = (__half*)alloc((size_t)N * 256 * 2);
    __half* buf2h  = xh;

    const int NB = (N + SCAN_CHUNK - 1) / SCAN_CHUNK;

    hipMemsetAsync(cnt, 0, (size_t)N * 4, stream);
    hipMemsetAsync(cursor, 0, (size_t)N * 4, stream);

    count_dst_kernel<<<(E + 255) / 256, 256, 0, stream>>>(dst, E, cnt);
    dinv_kernel<<<(N + 255) / 256, 256, 0, stream>>>(cnt, dinv, N);
    scan_phase1<<<NB, 256, 0, stream>>>(cnt, N, bsum);
    scan_phase2<<<1, 64, 0, stream>>>(bsum, NB, rowoff, N, E);
    scan_phase3<<<NB, 256, 0, stream>>>(cnt, N, bsum, rowoff);
    fill_csr<<<(E + 255) / 256, 256, 0, stream>>>(src, dst, E, rowoff, cursor, col);

    // pack x to fp16 (halves gather bytes of the dominant kernel)
    const int n8 = (N * 256) / 8;
    pack_half<<<(n8 + 255) / 256, 256, 0, stream>>>(x, xh, n8);

    // layer 1: aggregate xh (fp16 gather, f32 accum), then in-place row GEMM
    aggregate256_h<<<N, 64, 0, stream>>>(xh, dinv, rowoff, col, buf1);
    const int GB = (N + 63) / 64;
    gemm_rows<256, true, false, false><<<GB, 256, 0, stream>>>(buf1, W1, b1, nullptr, buf1, N);

    // layer 2: GEMM to 128-wide, dinv folded, fp16 output; then final aggregate
    gemm_rows<128, false, true, true><<<GB, 256, 0, stream>>>(buf1, W2, nullptr, dinv, buf2h, N);
    aggregate128_h_bias_relu<<<N, 64, 0, stream>>>(buf2h, dinv, rowoff, col, b2, out);
}

// Round 4
// 485.643 us; speedup vs baseline: 1.6674x; 1.3324x over previous
//
#include <hip/hip_runtime.h>
#include <hip/hip_fp16.h>

// ---------------------------------------------------------------------------
// 2-layer GCN encoder (PyG GCNConv semantics). fp16 storage + MFMA GEMMs,
// f32 accumulation everywhere.
// Pipeline:
//   1. CSR build (count / scan / fill) + dinv = 1/sqrt(deg+1)
//   2. xh    = fp16(x)
//   3. buf1h = fp16(Ahat @ xh)          [N,256]   (gather aggregate, f32 acc)
//   4. h1h   = fp16(relu(buf1h@W1+b1))  [N,256]   (MFMA GEMM, swapped ops)
//   5. buf2h = fp16((h1h@W2)*dinv[row]) [N,128]   (MFMA GEMM)
//   6. out   = relu(di*(buf2h[i]+sum buf2h[src]) + b2)   f32
// ---------------------------------------------------------------------------

typedef _Float16 f16x8 __attribute__((ext_vector_type(8)));
typedef float f32x4 __attribute__((ext_vector_type(4)));

constexpr int SCAN_CHUNK = 2048;   // 256 threads * 8 items

__global__ __launch_bounds__(256) void count_dst_kernel(const int* __restrict__ dst, int E,
                                                        int* __restrict__ cnt) {
    int e = blockIdx.x * 256 + threadIdx.x;
    if (e < E) atomicAdd(&cnt[dst[e]], 1);
}

__global__ __launch_bounds__(256) void dinv_kernel(const int* __restrict__ cnt,
                                                   float* __restrict__ dinv, int N) {
    int i = blockIdx.x * 256 + threadIdx.x;
    if (i < N) dinv[i] = 1.0f / sqrtf((float)(cnt[i] + 1));
}

__global__ __launch_bounds__(256) void scan_phase1(const int* __restrict__ cnt, int N,
                                                   int* __restrict__ bsum) {
    __shared__ int lds[256];
    int tid = threadIdx.x;
    int base = blockIdx.x * SCAN_CHUNK + tid * 8;
    int s = 0;
#pragma unroll
    for (int j = 0; j < 8; ++j) {
        int idx = base + j;
        if (idx < N) s += cnt[idx];
    }
    lds[tid] = s;
    __syncthreads();
    for (int o = 128; o > 0; o >>= 1) {
        if (tid < o) lds[tid] += lds[tid + o];
        __syncthreads();
    }
    if (tid == 0) bsum[blockIdx.x] = lds[0];
}

__global__ void scan_phase2(int* __restrict__ bsum, int nb, int* __restrict__ rowoff,
                            int N, int E) {
    if (threadIdx.x == 0) {
        int run = 0;
        for (int b = 0; b < nb; ++b) {
            int v = bsum[b];
            bsum[b] = run;
            run += v;
        }
        rowoff[N] = E;
    }
}

__global__ __launch_bounds__(256) void scan_phase3(const int* __restrict__ cnt, int N,
                                                   const int* __restrict__ bsum,
                                                   int* __restrict__ rowoff) {
    __shared__ int lds[256];
    int tid = threadIdx.x;
    int base = blockIdx.x * SCAN_CHUNK + tid * 8;
    int v[8];
    int tsum = 0;
#pragma unroll
    for (int j = 0; j < 8; ++j) {
        int idx = base + j;
        v[j] = (idx < N) ? cnt[idx] : 0;
        tsum += v[j];
    }
    lds[tid] = tsum;
    __syncthreads();
    for (int off = 1; off < 256; off <<= 1) {
        int x = (tid >= off) ? lds[tid - off] : 0;
        __syncthreads();
        lds[tid] += x;
        __syncthreads();
    }
    int run = bsum[blockIdx.x] + lds[tid] - tsum;  // exclusive base for this thread
#pragma unroll
    for (int j = 0; j < 8; ++j) {
        int idx = base + j;
        if (idx < N) rowoff[idx] = run;
        run += v[j];
    }
}

__global__ __launch_bounds__(256) void fill_csr(const int* __restrict__ src,
                                                const int* __restrict__ dst, int E,
                                                const int* __restrict__ rowoff,
                                                int* __restrict__ cursor,
                                                int* __restrict__ col) {
    int e = blockIdx.x * 256 + threadIdx.x;
    if (e < E) {
        int d = dst[e];
        int pos = atomicAdd(&cursor[d], 1);
        col[rowoff[d] + pos] = src[e];
    }
}

// f32 -> fp16 pack, 8 elems/thread
__global__ __launch_bounds__(256) void pack_half(const float* __restrict__ in,
                                                 __half* __restrict__ out, int n8) {
    int i = blockIdx.x * 256 + threadIdx.x;
    if (i < n8) {
        float4 a = ((const float4*)in)[(size_t)i * 2];
        float4 b = ((const float4*)in)[(size_t)i * 2 + 1];
        __half2 h[4];
        h[0] = __floats2half2_rn(a.x, a.y);
        h[1] = __floats2half2_rn(a.z, a.w);
        h[2] = __floats2half2_rn(b.x, b.y);
        h[3] = __floats2half2_rn(b.z, b.w);
        ((uint4*)out)[i] = *(const uint4*)h;
    }
}

// Pack W[K,NC] f32 into MFMA A-operand fragment order, fp16:
// Wp[((ks*NT+nt)*64+lane)*8 + j] = W[ks*32 + (lane>>4)*8 + j][nt*16 + (lane&15)]
__global__ __launch_bounds__(256) void pack_w(const float* __restrict__ W,
                                              __half* __restrict__ Wp, int NC, int total) {
    int t = blockIdx.x * 256 + threadIdx.x;
    if (t >= total) return;
    const int NT = NC / 16;
    int lane = t & 63;
    int rest = t >> 6;
    int nt = rest % NT;
    int ks = rest / NT;
    int n = nt * 16 + (lane & 15);
    int k0 = ks * 32 + (lane >> 4) * 8;
    __half tmp[8];
#pragma unroll
    for (int j = 0; j < 8; ++j) tmp[j] = __float2half_rn(W[(size_t)(k0 + j) * NC + n]);
    ((uint4*)Wp)[t] = *(const uint4*)tmp;
}

// buf1h[i,:] = fp16( dinv[i]*( dinv[i]*xh[i,:] + sum_e dinv[src]*xh[src,:] ) ), F=256
__global__ __launch_bounds__(64) void aggregate256_h(const __half* __restrict__ xh,
                                                     const float* __restrict__ dinv,
                                                     const int* __restrict__ rowoff,
                                                     const int* __restrict__ col,
                                                     __half* __restrict__ out) {
    int i = blockIdx.x;
    int lane = threadIdx.x;
    float di = dinv[i];
    const uint2* __restrict__ hv = (const uint2*)xh;  // 4 halves per slot
    uint2 raw = hv[(size_t)i * 64 + lane];
    float2 f0 = __half22float2(*(const __half2*)&raw.x);
    float2 f1 = __half22float2(*(const __half2*)&raw.y);
    float ax = di * f0.x, ay = di * f0.y, az = di * f1.x, aw = di * f1.y;
    int e0 = rowoff[i], e1 = rowoff[i + 1];
    int e = e0;
    for (; e + 8 <= e1; e += 8) {
        int s[8];
#pragma unroll
        for (int j = 0; j < 8; ++j) s[j] = col[e + j];
        float w[8];
#pragma unroll
        for (int j = 0; j < 8; ++j) w[j] = dinv[s[j]];
        uint2 u[8];
#pragma unroll
        for (int j = 0; j < 8; ++j) u[j] = hv[(size_t)s[j] * 64 + lane];
#pragma unroll
        for (int j = 0; j < 8; ++j) {
            float2 g0 = __half22float2(*(const __half2*)&u[j].x);
            float2 g1 = __half22float2(*(const __half2*)&u[j].y);
            ax = fmaf(w[j], g0.x, ax);
            ay = fmaf(w[j], g0.y, ay);
            az = fmaf(w[j], g1.x, az);
            aw = fmaf(w[j], g1.y, aw);
        }
    }
    for (; e < e1; ++e) {
        int s = col[e];
        float w = dinv[s];
        uint2 u = hv[(size_t)s * 64 + lane];
        float2 g0 = __half22float2(*(const __half2*)&u.x);
        float2 g1 = __half22float2(*(const __half2*)&u.y);
        ax = fmaf(w, g0.x, ax);
        ay = fmaf(w, g0.y, ay);
        az = fmaf(w, g1.x, az);
        aw = fmaf(w, g1.y, aw);
    }
    __half2 h0 = __floats2half2_rn(ax * di, ay * di);
    __half2 h1 = __floats2half2_rn(az * di, aw * di);
    uint2 o;
    o.x = *(const unsigned int*)&h0;
    o.y = *(const unsigned int*)&h1;
    ((uint2*)out)[(size_t)i * 64 + lane] = o;
}

// F=128 final aggregate over fp16 h (pre-scaled by dinv[src] in GEMM2 epilogue).
// out[i] = relu(di*(h[i]+sum h[src]) + b), f32 out.
__global__ __launch_bounds__(64) void aggregate128_h_bias_relu(const __half* __restrict__ h,
                                                               const float* __restrict__ dinv,
                                                               const int* __restrict__ rowoff,
                                                               const int* __restrict__ col,
                                                               const float* __restrict__ bias,
                                                               float* __restrict__ out) {
    int i = blockIdx.x;
    int lane = threadIdx.x;
    float di = dinv[i];
    const unsigned int* __restrict__ hv = (const unsigned int*)h;  // half2 per slot
    float2 v = __half22float2(*(const __half2*)&hv[(size_t)i * 64 + lane]);
    float ax = v.x, ay = v.y;
    int e0 = rowoff[i], e1 = rowoff[i + 1];
    int e = e0;
    for (; e + 8 <= e1; e += 8) {
        int s[8];
#pragma unroll
        for (int j = 0; j < 8; ++j) s[j] = col[e + j];
        unsigned int u[8];
#pragma unroll
        for (int j = 0; j < 8; ++j) u[j] = hv[(size_t)s[j] * 64 + lane];
#pragma unroll
        for (int j = 0; j < 8; ++j) {
            float2 g = __half22float2(*(const __half2*)&u[j]);
            ax += g.x;
            ay += g.y;
        }
    }
    for (; e < e1; ++e) {
        float2 g = __half22float2(*(const __half2*)&hv[(size_t)col[e] * 64 + lane]);
        ax += g.x;
        ay += g.y;
    }
    float2 bb = ((const float2*)bias)[lane];
    float2 r;
    r.x = fmaxf(fmaf(ax, di, bb.x), 0.f);
    r.y = fmaxf(fmaf(ay, di, bb.y), 0.f);
    ((float2*)out)[(size_t)i * 64 + lane] = r;
}

// MFMA GEMM: out[M,NC] = f(A[M,256] @ W[256,NC]) in fp16, f32 accum.
// Swapped operands: D = mfma(Wfrag, Xfrag) so each lane owns 4 consecutive
// output cols of one row -> packed 8B fp16 stores, no LDS.
// Block = 256 threads = 4 waves; wave w owns rows blockIdx.x*64 + w*16 + (lane&15).
template <int NC, bool BIAS_RELU, bool ROWSCALE>
__global__ __launch_bounds__(256) void gemm_mfma(const __half* __restrict__ A,
                                                 const __half* __restrict__ Wp,
                                                 const float* __restrict__ bias,
                                                 const float* __restrict__ rowscale,
                                                 __half* __restrict__ out, int M) {
    constexpr int NT = NC / 16;
    const int lane = threadIdx.x & 63;
    const int wave = threadIdx.x >> 6;
    const int kg = lane >> 4;  // 0..3 k-group
    const int row = blockIdx.x * 64 + wave * 16 + (lane & 15);
    const int rowc = (row < M) ? row : (M - 1);

    f32x4 acc[NT];
#pragma unroll
    for (int nt = 0; nt < NT; ++nt) acc[nt] = {0.f, 0.f, 0.f, 0.f};

    // X fragment base: lane reads A[rowc][ks*32 + kg*8 .. +7] (16B)
    const f16x8* __restrict__ Ap = (const f16x8*)(A + (size_t)rowc * 256 + kg * 8);
    const f16x8* __restrict__ Wf = (const f16x8*)Wp;

#pragma unroll
    for (int ks = 0; ks < 8; ++ks) {
        f16x8 xfrag = Ap[ks * 4];  // advance 32 halves per k-step
        const f16x8* wrow = Wf + (size_t)(ks * NT) * 64 + lane;
#pragma unroll
        for (int nt = 0; nt < NT; ++nt) {
            f16x8 wfrag = wrow[nt * 64];
            acc[nt] = __builtin_amdgcn_mfma_f32_16x16x32_f16(wfrag, xfrag, acc[nt], 0, 0, 0);
        }
    }

    if (row < M) {
        float rs = 1.0f;
        if constexpr (ROWSCALE) rs = rowscale[row];
#pragma unroll
        for (int nt = 0; nt < NT; ++nt) {
            const int n0 = nt * 16 + kg * 4;
            f32x4 v = acc[nt];
            if constexpr (BIAS_RELU) {
                float4 bb = *(const float4*)(bias + n0);
                v[0] = fmaxf(v[0] + bb.x, 0.f);
                v[1] = fmaxf(v[1] + bb.y, 0.f);
                v[2] = fmaxf(v[2] + bb.z, 0.f);
                v[3] = fmaxf(v[3] + bb.w, 0.f);
            }
            if constexpr (ROWSCALE) {
                v[0] *= rs; v[1] *= rs; v[2] *= rs; v[3] *= rs;
            }
            __half2 h0 = __floats2half2_rn(v[0], v[1]);
            __half2 h1 = __floats2half2_rn(v[2], v[3]);
            uint2 o;
            o.x = *(const unsigned int*)&h0;
            o.y = *(const unsigned int*)&h1;
            *(uint2*)(out + (size_t)row * NC + n0) = o;
        }
    }
}

extern "C" void kernel_launch(void* const* d_in, const int* in_sizes, int n_in,
                              void* d_out, int out_size, void* d_ws, size_t ws_size,
                              hipStream_t stream) {
    const float* x  = (const float*)d_in[0];
    const int*   ei = (const int*)d_in[1];
    const float* W1 = (const float*)d_in[2];
    const float* b1 = (const float*)d_in[3];
    const float* W2 = (const float*)d_in[4];
    const float* b2 = (const float*)d_in[5];
    float* out = (float*)d_out;

    const int N = in_sizes[0] / 256;
    const int E = in_sizes[1] / 2;
    const int* src = ei;
    const int* dst = ei + E;

    char* ws = (char*)d_ws;
    size_t off = 0;
    auto alloc = [&](size_t bytes) -> char* {
        char* p = ws + off;
        off += (bytes + 255) & ~(size_t)255;
        return p;
    };
    int*    cnt    = (int*)alloc((size_t)N * 4);
    int*    cursor = (int*)alloc((size_t)N * 4);
    int*    rowoff = (int*)alloc((size_t)(N + 1) * 4);
    int*    bsum   = (int*)alloc(4096);
    float*  dinv   = (float*)alloc((size_t)N * 4);
    int*    col    = (int*)alloc((size_t)E * 4);
    __half* Wp1    = (__half*)alloc((size_t)256 * 256 * 2);
    __half* Wp2    = (__half*)alloc((size_t)256 * 128 * 2);
    // bufA: xh (dead after agg1), then h1h (written by GEMM1)
    __half* bufA   = (__half*)alloc((size_t)N * 256 * 2);
    // bufB: buf1h (dead after GEMM1), then buf2h (written by GEMM2)
    __half* bufB   = (__half*)alloc((size_t)N * 256 * 2);
    __half* xh    = bufA;
    __half* h1h   = bufA;
    __half* buf1h = bufB;
    __half* buf2h = bufB;

    const int NB = (N + SCAN_CHUNK - 1) / SCAN_CHUNK;

    hipMemsetAsync(cnt, 0, (size_t)N * 4, stream);
    hipMemsetAsync(cursor, 0, (size_t)N * 4, stream);

    count_dst_kernel<<<(E + 255) / 256, 256, 0, stream>>>(dst, E, cnt);
    dinv_kernel<<<(N + 255) / 256, 256, 0, stream>>>(cnt, dinv, N);
    scan_phase1<<<NB, 256, 0, stream>>>(cnt, N, bsum);
    scan_phase2<<<1, 64, 0, stream>>>(bsum, NB, rowoff, N, E);
    scan_phase3<<<NB, 256, 0, stream>>>(cnt, N, bsum, rowoff);
    fill_csr<<<(E + 255) / 256, 256, 0, stream>>>(src, dst, E, rowoff, cursor, col);

    // weight + input packing
    pack_w<<<(8 * 16 * 64 + 255) / 256, 256, 0, stream>>>(W1, Wp1, 256, 8 * 16 * 64);
    pack_w<<<(8 * 8 * 64 + 255) / 256, 256, 0, stream>>>(W2, Wp2, 128, 8 * 8 * 64);
    const int n8 = (N * 256) / 8;
    pack_half<<<(n8 + 255) / 256, 256, 0, stream>>>(x, xh, n8);

    // layer 1: aggregate (fp16 gather, f32 accum, fp16 out), then MFMA GEMM
    aggregate256_h<<<N, 64, 0, stream>>>(xh, dinv, rowoff, col, buf1h);
    const int GB = (N + 63) / 64;
    gemm_mfma<256, true, false><<<GB, 256, 0, stream>>>(buf1h, Wp1, b1, nullptr, h1h, N);

    // layer 2: MFMA GEMM to 128-wide with dinv folded, then final aggregate
    gemm_mfma<128, false, true><<<GB, 256, 0, stream>>>(h1h, Wp2, nullptr, dinv, buf2h, N);
    aggregate128_h_bias_relu<<<N, 64, 0, stream>>>(buf2h, dinv, rowoff, col, b2, out);
}